// Round 1
// baseline (1427.268 us; speedup 1.0000x reference)
//
#include <hip/hip_runtime.h>

typedef unsigned short u16;
typedef __attribute__((ext_vector_type(4))) float f32x4;
typedef __attribute__((ext_vector_type(8))) short s16x8;
typedef __attribute__((ext_vector_type(4))) int i32x4;

#define EPS 1e-5f

// ---------- helpers ----------
__device__ __forceinline__ u16 f2bf(float f) {
  unsigned u = __float_as_uint(f);
  return (u16)((u + 0x7fffu + ((u >> 16) & 1u)) >> 16);
}
__device__ __forceinline__ float sigm(float x) { return 1.0f / (1.0f + __expf(-x)); }
__device__ __forceinline__ float tanh_f(float x) {
  float e = __expf(-2.0f * fabsf(x));
  float r = (1.0f - e) / (1.0f + e);
  return copysignf(r, x);
}

// ---------- weight pack: conv_w (512,192,5) f32 -> per-fragment bf16 ----------
// frag f = ((tap*6+kk)*8 + mt)*4 + mi ; element = lane*8 + j
// A[o][c] with o = mt*64+mi*16+(lane&15), c = kk*32+8*(lane>>4)+j
__global__ __launch_bounds__(256) void k_wcvt(const float* __restrict__ w, u16* __restrict__ Wpk) {
  int idx = blockIdx.x * 256 + threadIdx.x;   // exactly 491520 threads
  int f = idx >> 9, r = idx & 511;
  int lane = r >> 3, j = r & 7;
  int mi = f & 3, mt = (f >> 2) & 7, tk = f >> 5;
  int kk = tk % 6, tap = tk / 6;
  int o = (mt << 6) + (mi << 4) + (lane & 15);
  int c = (kk << 5) + ((lane >> 4) << 3) + j;
  Wpk[idx] = f2bf(w[(o * 192 + c) * 5 + tap]);
}

// ---------- x transpose: inputs (t,b,64,256) f32 -> xT[t*32+b][264 rows][64 c] bf16, swizzled ----------
__global__ __launch_bounds__(256) void k_xtrans(const float* __restrict__ x, u16* __restrict__ xT) {
  int tb = blockIdx.x;
  int tid = threadIdx.x;
  __shared__ __align__(16) u16 ltile[256 * 72];
  const float* src = x + tb * (64 * 256);
  for (int it = 0; it < 64; ++it) {
    int idx = it * 256 + tid;
    int c = idx >> 8, l = idx & 255;
    ltile[l * 72 + c] = f2bf(src[idx]);
  }
  __syncthreads();
  char* dst = (char*)(xT + tb * 16896);   // 264*64 u16 = 33792 B
  i32x4 z = {0, 0, 0, 0};
  for (int i = tid; i < 2112; i += 256) { // 264 rows * 8 chunks
    int r = i >> 3, ch = i & 7;
    i32x4 v = z;
    if (r >= 2 && r < 258) v = *(const i32x4*)(ltile + (r - 2) * 72 + ch * 8);
    *(i32x4*)(dst + r * 128 + ((ch * 16) ^ ((r & 7) << 4))) = v;
  }
}

// ---------- zero h-state, c-state, stats ----------
__global__ void k_init(i32x4* __restrict__ hT, i32x4* __restrict__ cx, i32x4* __restrict__ st) {
  int n = gridDim.x * blockDim.x;
  int tid = blockIdx.x * blockDim.x + threadIdx.x;
  i32x4 z = {0, 0, 0, 0};
  for (int i = tid; i < 135168; i += n) hT[i] = z;   // 32*264*128 u16
  for (int i = tid; i < 262144; i += n) cx[i] = z;   // 32*128*256 f32
  for (int i = tid; i < 8192;   i += n) st[i] = z;   // 32*32*16*2 f32
}

// ---------- conv + bias + fused GN partial stats ----------
// grid 512 = b(32) x mt(8) x lt(2); block 128 (2 waves), wave tile 64x64
__global__ __launch_bounds__(128) void k_conv(
    const u16* __restrict__ Wpk, const u16* __restrict__ xT, const u16* __restrict__ hT,
    const float* __restrict__ cb, float* __restrict__ gates, float* __restrict__ stats, int t) {
  int bi = blockIdx.x;
  int b = bi >> 4, mt = (bi >> 1) & 7, lt = bi & 1;
  int m0 = mt << 6, l0 = lt << 7;
  int tid = threadIdx.x, wave = tid >> 6, lane = tid & 63;
  __shared__ __align__(16) char ldsx[17408];   // 136 rows x 128 B
  __shared__ __align__(16) char ldsh[33792];   // 132 rows x 256 B
  __shared__ float red[2][2][2];

  {
    const i32x4* gx = (const i32x4*)((const char*)(xT + (((t << 5) + b) * 16896)) + (l0 << 7));
    i32x4* lx = (i32x4*)ldsx;
    for (int i = tid; i < 1088; i += 128) lx[i] = gx[i];
    const i32x4* gh = (const i32x4*)((const char*)(hT + b * 33792) + (l0 << 8));
    i32x4* lh = (i32x4*)ldsh;
    for (int i = tid; i < 2112; i += 128) lh[i] = gh[i];
  }
  __syncthreads();

  f32x4 zero4 = {0.f, 0.f, 0.f, 0.f};
  f32x4 acc[4][4];
  #pragma unroll
  for (int mi = 0; mi < 4; ++mi)
    #pragma unroll
    for (int ni = 0; ni < 4; ++ni) acc[mi][ni] = zero4;

  const s16x8* Wv = (const s16x8*)Wpk;
  int cgrp = (lane >> 4) << 4;   // byte offset of this lane's 8-elem c-group

  for (int tap = 0; tap < 5; ++tap) {
    #pragma unroll
    for (int kk = 0; kk < 6; ++kk) {
      int fb = ((tap * 6 + kk) << 5) + (mt << 2);
      s16x8 av[4];
      #pragma unroll
      for (int mi = 0; mi < 4; ++mi) av[mi] = Wv[((fb + mi) << 6) + lane];
      s16x8 bv[4];
      #pragma unroll
      for (int ni = 0; ni < 4; ++ni) {
        int colL = (wave << 6) + (ni << 4) + (lane & 15);
        int row = colL + tap;
        int sw = (row & 7) << 4;
        const char* p;
        if (kk < 2) p = ldsx + (row << 7) + (((kk << 6) + cgrp) ^ sw);
        else        p = ldsh + (row << 8) + ((((kk - 2) << 6) + cgrp) ^ sw);
        bv[ni] = *(const s16x8*)p;
      }
      #pragma unroll
      for (int mi = 0; mi < 4; ++mi)
        #pragma unroll
        for (int ni = 0; ni < 4; ++ni)
          acc[mi][ni] = __builtin_amdgcn_mfma_f32_16x16x32_bf16(av[mi], bv[ni], acc[mi][ni], 0, 0, 0);
    }
  }

  // epilogue: +bias, store gates, fused group stats (block rows = 2 full groups over this half-L)
  float sum[2] = {0.f, 0.f}, sq[2] = {0.f, 0.f};
  #pragma unroll
  for (int mi = 0; mi < 4; ++mi) {
    int o0 = m0 + (mi << 4) + ((lane >> 4) << 2);
    f32x4 bias = *(const f32x4*)(cb + o0);
    int g = mi >> 1;
    #pragma unroll
    for (int ni = 0; ni < 4; ++ni) {
      int l = l0 + (wave << 6) + (ni << 4) + (lane & 15);
      f32x4 v = acc[mi][ni];
      #pragma unroll
      for (int r = 0; r < 4; ++r) {
        float val = v[r] + bias[r];
        gates[(((b << 9) + o0 + r) << 8) + l] = val;
        sum[g] += val; sq[g] += val * val;
      }
    }
  }
  #pragma unroll
  for (int off = 1; off < 64; off <<= 1) {
    sum[0] += __shfl_xor(sum[0], off); sq[0] += __shfl_xor(sq[0], off);
    sum[1] += __shfl_xor(sum[1], off); sq[1] += __shfl_xor(sq[1], off);
  }
  if (lane == 0) {
    red[wave][0][0] = sum[0]; red[wave][0][1] = sq[0];
    red[wave][1][0] = sum[1]; red[wave][1][1] = sq[1];
  }
  __syncthreads();
  if (tid < 4) {   // 2 blocks contribute per counter -> commutative -> deterministic
    int g = tid >> 1, j = tid & 1;
    float v = red[0][g][j] + red[1][g][j];
    atomicAdd(&stats[((((t << 5) + b) << 4) + (mt << 1) + g) * 2 + j], v);
  }
}

// ---------- GN apply + LSTM pointwise + transposed/swizzled h write ----------
// grid 256 = b(32) x l-tile(8 of 32); block 256
__global__ __launch_bounds__(256) void k_point(
    const float* __restrict__ gates, const float* __restrict__ stats,
    const float* __restrict__ gnw, const float* __restrict__ gnb,
    float* __restrict__ cx, u16* __restrict__ hT, float* __restrict__ out, int t) {
  int bi = blockIdx.x;
  int b = bi >> 3, l0 = (bi & 7) << 5;
  int tid = threadIdx.x;
  __shared__ __align__(16) u16 hl[4096];
  int lr = tid & 31, l = l0 + lr;
  int c0 = tid >> 5;
  const float inv = 1.0f / 8192.0f;
  const float* st = stats + (((t << 5) + b) << 5);
  float* outp = out + (((t << 5) + b) << 15);
  int sw = ((l + 2) & 7) << 3;
  for (int ci = 0; ci < 16; ++ci) {
    int c = (ci << 3) + c0;
    int gI = c >> 5;
    float muI = st[gI * 2] * inv;
    float rsI = rsqrtf(st[gI * 2 + 1] * inv - muI * muI + EPS);
    float muF = st[(gI + 4) * 2] * inv;
    float rsF = rsqrtf(st[(gI + 4) * 2 + 1] * inv - muF * muF + EPS);
    float muG = st[(gI + 8) * 2] * inv;
    float rsG = rsqrtf(st[(gI + 8) * 2 + 1] * inv - muG * muG + EPS);
    float muO = st[(gI + 12) * 2] * inv;
    float rsO = rsqrtf(st[(gI + 12) * 2 + 1] * inv - muO * muO + EPS);
    int base = (((b << 9) + c) << 8) + l;
    float vi = gates[base];
    float vf = gates[base + (128 << 8)];
    float vg = gates[base + (256 << 8)];
    float vo = gates[base + (384 << 8)];
    vi = (vi - muI) * rsI * gnw[c]       + gnb[c];
    vf = (vf - muF) * rsF * gnw[c + 128] + gnb[c + 128];
    vg = (vg - muG) * rsG * gnw[c + 256] + gnb[c + 256];
    vo = (vo - muO) * rsO * gnw[c + 384] + gnb[c + 384];
    int cxi = (((b << 7) + c) << 8) + l;
    float cyv = sigm(vf) * cx[cxi] + sigm(vi) * tanh_f(vg);
    float hyv = sigm(vo) * tanh_f(cyv);
    cx[cxi] = cyv;
    outp[(c << 8) + l] = hyv;
    hl[(lr << 7) + (c ^ sw)] = f2bf(hyv);
    if (t == 31) {
      out[33554432 + cxi] = hyv;   // final hy
      out[34603008 + cxi] = cyv;   // final cy
    }
  }
  __syncthreads();
  i32x4* dst = (i32x4*)(hT + b * 33792 + ((l0 + 2) << 7));
  const i32x4* srcv = (const i32x4*)hl;
  for (int i = tid; i < 512; i += 256) dst[i] = srcv[i];
}

// ---------- launch ----------
extern "C" void kernel_launch(void* const* d_in, const int* in_sizes, int n_in,
                              void* d_out, int out_size, void* d_ws, size_t ws_size,
                              hipStream_t stream) {
  const float* x  = (const float*)d_in[0];
  const float* cw = (const float*)d_in[1];
  const float* cb = (const float*)d_in[2];
  const float* gw = (const float*)d_in[3];
  const float* gb = (const float*)d_in[4];
  float* out = (float*)d_out;
  char* ws = (char*)d_ws;

  u16*   Wpk   = (u16*)(ws);                 //   983,040 B
  u16*   xT    = (u16*)(ws + 983040);        //  34,603,008 B
  u16*   hT    = (u16*)(ws + 35586048);      //   2,162,688 B
  float* cx    = (float*)(ws + 37748736);    //   4,194,304 B
  float* gates = (float*)(ws + 41943040);    //  16,777,216 B
  float* stats = (float*)(ws + 58720256);    //     131,072 B   (total ~56.1 MB)

  k_wcvt<<<1920, 256, 0, stream>>>(cw, Wpk);
  k_xtrans<<<1024, 256, 0, stream>>>(x, xT);
  k_init<<<512, 256, 0, stream>>>((i32x4*)hT, (i32x4*)cx, (i32x4*)stats);
  for (int t = 0; t < 32; ++t) {
    k_conv<<<512, 128, 0, stream>>>(Wpk, xT, hT, cb, gates, stats, t);
    k_point<<<256, 256, 0, stream>>>(gates, stats, gw, gb, cx, hT, out, t);
  }
}

// Round 2
// 821.082 us; speedup vs baseline: 1.7383x; 1.7383x over previous
//
#include <hip/hip_runtime.h>

typedef unsigned short u16;
typedef __attribute__((ext_vector_type(4))) float f32x4;
typedef __attribute__((ext_vector_type(8))) short s16x8;
typedef __attribute__((ext_vector_type(4))) int i32x4;

#define EPS 1e-5f

// ---------- helpers ----------
__device__ __forceinline__ u16 f2bf(float f) {
  unsigned u = __float_as_uint(f);
  return (u16)((u + 0x7fffu + ((u >> 16) & 1u)) >> 16);
}
__device__ __forceinline__ float sigm(float x) { return 1.0f / (1.0f + __expf(-x)); }
__device__ __forceinline__ float tanh_f(float x) {
  float e = __expf(-2.0f * fabsf(x));
  float r = (1.0f - e) / (1.0f + e);
  return copysignf(r, x);
}

// ---------- weight pack: conv_w (512,192,5) f32 -> per-fragment bf16 ----------
// f = (tap*6+kk)*32 + of ; of = o>>4 ; element = lane*8+j
// A[o][c]: o = of*16 + (lane&15), c = kk*32 + (lane>>4)*8 + j
__global__ __launch_bounds__(256) void k_wcvt(const float* __restrict__ w, u16* __restrict__ Wpk) {
  int idx = blockIdx.x * 256 + threadIdx.x;   // exactly 491520 threads
  int f = idx >> 9, r = idx & 511;
  int lane = r >> 3, j = r & 7;
  int of = f & 31, tk = f >> 5;
  int kk = tk % 6, tap = tk / 6;
  int o = (of << 4) + (lane & 15);
  int c = (kk << 5) + ((lane >> 4) << 3) + j;
  Wpk[idx] = f2bf(w[(o * 192 + c) * 5 + tap]);
}

// ---------- x transpose: inputs (t,b,64,256) f32 -> xT[t*32+b][264 rows][64 c] bf16, swizzled ----------
__global__ __launch_bounds__(256) void k_xtrans(const float* __restrict__ x, u16* __restrict__ xT) {
  int tb = blockIdx.x;
  int tid = threadIdx.x;
  __shared__ __align__(16) u16 ltile[256 * 72];
  const float* src = x + tb * (64 * 256);
  for (int it = 0; it < 64; ++it) {
    int idx = it * 256 + tid;
    int c = idx >> 8, l = idx & 255;
    ltile[l * 72 + c] = f2bf(src[idx]);
  }
  __syncthreads();
  char* dst = (char*)(xT + tb * 16896);   // 264*64 u16 = 33792 B
  i32x4 z = {0, 0, 0, 0};
  for (int i = tid; i < 2112; i += 256) { // 264 rows * 8 chunks
    int r = i >> 3, ch = i & 7;
    i32x4 v = z;
    if (r >= 2 && r < 258) v = *(const i32x4*)(ltile + (r - 2) * 72 + ch * 8);
    *(i32x4*)(dst + r * 128 + ((ch * 16) ^ ((r & 7) << 4))) = v;
  }
}

// ---------- zero h-state (both ping-pong buffers) + c-state ----------
__global__ void k_init(i32x4* __restrict__ hT, i32x4* __restrict__ cx) {
  int n = gridDim.x * blockDim.x;
  int tid = blockIdx.x * blockDim.x + threadIdx.x;
  i32x4 z = {0, 0, 0, 0};
  for (int i = tid; i < 270336; i += n) hT[i] = z;   // 2 x 32*264*128 u16
  for (int i = tid; i < 262144; i += n) cx[i] = z;   // 32*128*256 f32
}

// ---------- fused: conv + bias + GN + LSTM pointwise + transposed h write ----------
// grid 128 = b(32) x cs(4); block 512 (8 waves = 2 row-halves x 4 L-quarters)
// Block owns channels [32cs,32cs+32) of EACH gate -> 4 complete GN groups + full LSTM cells.
// Wave m-frags = the 4 gates for the same 16 channels -> pointwise is wave-local.
__global__ __launch_bounds__(512, 2) void k_step(
    const u16* __restrict__ Wpk, const u16* __restrict__ xT, u16* __restrict__ hT,
    const float* __restrict__ cb, const float* __restrict__ gnw, const float* __restrict__ gnb,
    float* __restrict__ cx, float* __restrict__ out, int t) {
  int b = blockIdx.x >> 2, cs = blockIdx.x & 3;
  int tid = threadIdx.x, wave = tid >> 6, lane = tid & 63;
  int wrow = wave & 1, wcol = wave >> 1;

  __shared__ __align__(16) char ldsx[33792];   // 264 rows x 128 B (x, swizzled)
  __shared__ __align__(16) char ldsh[67584];   // 264 rows x 256 B (h, swizzled)
  __shared__ float red[8][4][2];
  __shared__ __align__(16) char hl[16384];     // 256 L x 64 B (32 ch bf16, 16B-granule swizzled)

  const u16* hTr = hT + (t & 1) * 1081344;          // read buffer (prev h)
  u16* hTw = hT + ((t + 1) & 1) * 1081344;          // write buffer (next h)

  // ---- stage x & h slices (already swizzled in global) ----
  {
    const i32x4* gx = (const i32x4*)(xT + ((t << 5) + b) * 16896);
    i32x4* lx = (i32x4*)ldsx;
    for (int i = tid; i < 2112; i += 512) lx[i] = gx[i];
    const i32x4* gh = (const i32x4*)(hTr + b * 33792);
    i32x4* lh = (i32x4*)ldsh;
    for (int i = tid; i < 4224; i += 512) lh[i] = gh[i];
  }
  __syncthreads();

  // ---- conv GEMM: M=4 gates x 16ch, N=64 L, K=960 ----
  f32x4 zero4 = {0.f, 0.f, 0.f, 0.f};
  f32x4 acc[4][4];
  #pragma unroll
  for (int g = 0; g < 4; ++g)
    #pragma unroll
    for (int ni = 0; ni < 4; ++ni) acc[g][ni] = zero4;

  const s16x8* Wv = (const s16x8*)Wpk;
  int ofbase = (cs << 1) + wrow;       // of = 8*gate + ofbase
  int cgrp = (lane >> 4) << 4;         // byte offset of lane's 8-ch k-group

  for (int tap = 0; tap < 5; ++tap) {
    #pragma unroll
    for (int kk = 0; kk < 6; ++kk) {
      int fb = ((tap * 6 + kk) << 5) + ofbase;
      s16x8 av[4];
      #pragma unroll
      for (int g = 0; g < 4; ++g) av[g] = Wv[((fb + (g << 3)) << 6) + lane];
      s16x8 bv[4];
      #pragma unroll
      for (int ni = 0; ni < 4; ++ni) {
        int row = (wcol << 6) + (ni << 4) + (lane & 15) + tap;  // input row l+tap (tile has +2 halo)
        int sw = (row & 7) << 4;
        const char* p;
        if (kk < 2) p = ldsx + (row << 7) + (((kk << 6) + cgrp) ^ sw);
        else        p = ldsh + (row << 8) + ((((kk - 2) << 6) + cgrp) ^ sw);
        bv[ni] = *(const s16x8*)p;
      }
      #pragma unroll
      for (int g = 0; g < 4; ++g)
        #pragma unroll
        for (int ni = 0; ni < 4; ++ni)
          acc[g][ni] = __builtin_amdgcn_mfma_f32_16x16x32_bf16(av[g], bv[ni], acc[g][ni], 0, 0, 0);
    }
  }

  // ---- + bias, per-gate group stats (group = 32 ch x 256 L, fully in-block) ----
  int ch16 = (lane >> 4) << 2;                    // channel quarter within 16
  int cbase = (cs << 5) + (wrow << 4) + ch16;     // hy channel base (0..127) for r=0
  float sum[4], sq[4];
  #pragma unroll
  for (int g = 0; g < 4; ++g) {
    f32x4 bias = *(const f32x4*)(cb + (g << 7) + cbase);
    sum[g] = 0.f; sq[g] = 0.f;
    #pragma unroll
    for (int ni = 0; ni < 4; ++ni)
      #pragma unroll
      for (int r = 0; r < 4; ++r) {
        float v = acc[g][ni][r] + bias[r];
        acc[g][ni][r] = v;
        sum[g] += v; sq[g] += v * v;
      }
  }
  #pragma unroll
  for (int off = 1; off < 64; off <<= 1) {
    #pragma unroll
    for (int g = 0; g < 4; ++g) {
      sum[g] += __shfl_xor(sum[g], off);
      sq[g]  += __shfl_xor(sq[g], off);
    }
  }
  if (lane == 0) {
    #pragma unroll
    for (int g = 0; g < 4; ++g) { red[wave][g][0] = sum[g]; red[wave][g][1] = sq[g]; }
  }
  __syncthreads();

  const float inv = 1.0f / 8192.0f;
  float mu[4], rs[4];
  #pragma unroll
  for (int g = 0; g < 4; ++g) {
    float s = 0.f, q = 0.f;
    #pragma unroll
    for (int w = 0; w < 8; ++w) { s += red[w][g][0]; q += red[w][g][1]; }
    mu[g] = s * inv;
    rs[g] = rsqrtf(q * inv - mu[g] * mu[g] + EPS);
  }

  // ---- GN apply + LSTM pointwise (wave-local) ----
  float w4[4][4], b4[4][4];
  #pragma unroll
  for (int g = 0; g < 4; ++g)
    #pragma unroll
    for (int r = 0; r < 4; ++r) {
      int c = (g << 7) + cbase + r;
      w4[g][r] = gnw[c]; b4[g][r] = gnb[c];
    }

  float* outp = out + (((t << 5) + b) << 15);
  int lhalf = lane & 15;
  #pragma unroll
  for (int ni = 0; ni < 4; ++ni) {
    int l = (wcol << 6) + (ni << 4) + lhalf;
    u16 hp[4];
    #pragma unroll
    for (int r = 0; r < 4; ++r) {
      int c = cbase + r;
      float vi = (acc[0][ni][r] - mu[0]) * rs[0] * w4[0][r] + b4[0][r];
      float vf = (acc[1][ni][r] - mu[1]) * rs[1] * w4[1][r] + b4[1][r];
      float vg = (acc[2][ni][r] - mu[2]) * rs[2] * w4[2][r] + b4[2][r];
      float vo = (acc[3][ni][r] - mu[3]) * rs[3] * w4[3][r] + b4[3][r];
      int cxi = (((b << 7) + c) << 8) + l;
      float cyv = sigm(vf) * cx[cxi] + sigm(vi) * tanh_f(vg);
      float hyv = sigm(vo) * tanh_f(cyv);
      cx[cxi] = cyv;
      outp[(c << 8) + l] = hyv;
      hp[r] = f2bf(hyv);
      if (t == 31) {
        out[33554432 + cxi] = hyv;   // final hy
        out[34603008 + cxi] = cyv;   // final cy
      }
    }
    // pack 4 consecutive channels -> 8B write to hl (swizzled by l&3 at 16B granularity)
    int gran = (wrow << 5) + (ch16 << 1);                       // 8B-granule byte offset
    *(unsigned long long*)(hl + (l << 6) + (gran ^ ((l & 3) << 4))) =
        *(const unsigned long long*)hp;
  }
  __syncthreads();

  // ---- cooperative transposed h write: 32 ch stripe -> hTw (swizzled rows) ----
  char* dsth = (char*)(hTw + b * 33792);
  #pragma unroll
  for (int i = tid; i < 1024; i += 512) {
    int l = i >> 2, k = i & 3;
    int row = l + 2;
    i32x4 v = *(const i32x4*)(hl + (l << 6) + ((k << 4) ^ ((l & 3) << 4)));
    int c16 = (cs << 2) + k;
    *(i32x4*)(dsth + (row << 8) + ((c16 << 4) ^ ((row & 7) << 4))) = v;
  }
}

// ---------- launch ----------
extern "C" void kernel_launch(void* const* d_in, const int* in_sizes, int n_in,
                              void* d_out, int out_size, void* d_ws, size_t ws_size,
                              hipStream_t stream) {
  const float* x  = (const float*)d_in[0];
  const float* cw = (const float*)d_in[1];
  const float* cb = (const float*)d_in[2];
  const float* gw = (const float*)d_in[3];
  const float* gb = (const float*)d_in[4];
  float* out = (float*)d_out;
  char* ws = (char*)d_ws;

  u16*   Wpk = (u16*)(ws);                 //     983,040 B
  u16*   xT  = (u16*)(ws + 983040);        //  34,603,008 B
  u16*   hT  = (u16*)(ws + 35586048);      //   4,325,376 B (2 ping-pong buffers)
  float* cx  = (float*)(ws + 39911424);    //   4,194,304 B  (total ~44.1 MB)

  k_wcvt<<<1920, 256, 0, stream>>>(cw, Wpk);
  k_xtrans<<<1024, 256, 0, stream>>>(x, xT);
  k_init<<<512, 256, 0, stream>>>((i32x4*)hT, (i32x4*)cx);
  for (int t = 0; t < 32; ++t)
    k_step<<<128, 512, 0, stream>>>(Wpk, xT, hT, cb, gw, gb, cx, out, t);
}

// Round 3
// 699.875 us; speedup vs baseline: 2.0393x; 1.1732x over previous
//
#include <hip/hip_runtime.h>

typedef unsigned short u16;
typedef unsigned int u32;
typedef __attribute__((ext_vector_type(4))) float f32x4;
typedef __attribute__((ext_vector_type(8))) short s16x8;
typedef __attribute__((ext_vector_type(4))) int i32x4;

#define EPS 1e-5f

// ---------- helpers ----------
__device__ __forceinline__ u16 f2bf(float f) {
  unsigned u = __float_as_uint(f);
  return (u16)((u + 0x7fffu + ((u >> 16) & 1u)) >> 16);
}
__device__ __forceinline__ float sigm(float x) { return 1.0f / (1.0f + __expf(-x)); }
__device__ __forceinline__ float tanh_f(float x) {
  float e = __expf(-2.0f * fabsf(x));
  float r = (1.0f - e) / (1.0f + e);
  return copysignf(r, x);
}
__device__ __forceinline__ void gl_lds16(const void* g, void* l) {
  __builtin_amdgcn_global_load_lds(
      (const __attribute__((address_space(1))) u32*)g,
      (__attribute__((address_space(3))) u32*)l, 16, 0, 0);
}

// ---------- weight pack: conv_w (512,192,5) f32 -> per-fragment bf16 ----------
// f = (tap*6+kk)*32 + of ; of = o>>4 ; element = lane*8+j
// A[o][c]: o = of*16 + (lane&15), c = kk*32 + (lane>>4)*8 + j
__global__ __launch_bounds__(256) void k_wcvt(const float* __restrict__ w, u16* __restrict__ Wpk) {
  int idx = blockIdx.x * 256 + threadIdx.x;   // exactly 491520 threads
  int f = idx >> 9, r = idx & 511;
  int lane = r >> 3, j = r & 7;
  int of = f & 31, tk = f >> 5;
  int kk = tk % 6, tap = tk / 6;
  int o = (of << 4) + (lane & 15);
  int c = (kk << 5) + ((lane >> 4) << 3) + j;
  Wpk[idx] = f2bf(w[(o * 192 + c) * 5 + tap]);
}

// ---------- x transpose: inputs (t,b,64,256) f32 -> xT[t*32+b][264 rows][64 c] bf16, swizzled ----------
__global__ __launch_bounds__(256) void k_xtrans(const float* __restrict__ x, u16* __restrict__ xT) {
  int tb = blockIdx.x;
  int tid = threadIdx.x;
  __shared__ __align__(16) u16 ltile[256 * 72];
  const float* src = x + tb * (64 * 256);
  for (int it = 0; it < 64; ++it) {
    int idx = it * 256 + tid;
    int c = idx >> 8, l = idx & 255;
    ltile[l * 72 + c] = f2bf(src[idx]);
  }
  __syncthreads();
  char* dst = (char*)(xT + tb * 16896);   // 264*64 u16 = 33792 B
  i32x4 z = {0, 0, 0, 0};
  for (int i = tid; i < 2112; i += 256) { // 264 rows * 8 chunks
    int r = i >> 3, ch = i & 7;
    i32x4 v = z;
    if (r >= 2 && r < 258) v = *(const i32x4*)(ltile + (r - 2) * 72 + ch * 8);
    *(i32x4*)(dst + r * 128 + ((ch * 16) ^ ((r & 7) << 4))) = v;
  }
}

// ---------- zero h-state (both buffers) + c-state + flags ----------
__global__ void k_init(i32x4* __restrict__ hT, i32x4* __restrict__ cxv, i32x4* __restrict__ flg) {
  int n = gridDim.x * blockDim.x;
  int tid = blockIdx.x * blockDim.x + threadIdx.x;
  i32x4 z = {0, 0, 0, 0};
  for (int i = tid; i < 270336; i += n) hT[i] = z;   // 2 x 32*264*128 u16
  for (int i = tid; i < 262144; i += n) cxv[i] = z;  // 32*128*256 f32
  for (int i = tid; i < 2048;   i += n) flg[i] = z;  // 8192 int flags
}

// ---------- fused step: conv + bias + GN(partner exchange) + LSTM + h write ----------
// grid 256 = b(32) x cs(4) x lh(2); block 512 = 8 waves (wrow 2 x wcol 4)
// Block tile: 128 gate-ch (32 hy-ch x 4 gates) x 128 L. Wave: 64 gate-ch x 32 L.
__global__ __launch_bounds__(512) void k_step(
    const u16* __restrict__ Wpk, const u16* __restrict__ xT, u16* __restrict__ hT,
    const float* __restrict__ cb, const float* __restrict__ gnw, const float* __restrict__ gnb,
    float* __restrict__ cx, float* __restrict__ out,
    float* __restrict__ stats, int* __restrict__ flags, int t) {
  int blk = blockIdx.x;
  int b = blk >> 3, cs = (blk >> 1) & 3, lh = blk & 1;
  int tid = threadIdx.x, wave = tid >> 6, lane = tid & 63;
  int wrow = wave & 1, wcol = wave >> 1;

  __shared__ __align__(16) char ldsx[16896];      // 132 rows x 128 B (swizzled)
  __shared__ __align__(16) char ldsh[33792];      // 132 rows x 256 B (swizzled)
  __shared__ __align__(16) char A_lds[4][8192];   // quad-buffered A k-chunks
  __shared__ __align__(16) char hl[8192];         // 128 L x 64 B
  __shared__ float red[8][4][2];
  __shared__ float smu[4], srs[4];

  const u16* hTr = hT + (t & 1) * 1081344;
  u16* hTw = hT + ((t + 1) & 1) * 1081344;

  int ofw = ((wave >> 1) << 3) + (cs << 1) + (wave & 1);   // frag 'wave' <-> of
  // ---- prologue: issue A chunks 0,1 + stage x/h via global_load_lds ----
  gl_lds16(Wpk + ((ofw << 6) + lane) * 8, A_lds[0] + (wave << 10));
  gl_lds16(Wpk + (((32 + ofw) << 6) + lane) * 8, A_lds[1] + (wave << 10));
  {
    const char* gx = (const char*)(xT + ((t << 5) + b) * 16896 + (lh << 13));
    for (int i = tid; i < 1056; i += 512)
      gl_lds16(gx + (i << 4), ldsx + ((i >> 6) << 10));
    const char* gh = (const char*)(hTr + b * 33792 + (lh << 14));
    for (int i = tid; i < 2112; i += 512)
      gl_lds16(gh + (i << 4), ldsh + ((i >> 6) << 10));
  }
  asm volatile("s_waitcnt vmcnt(0) lgkmcnt(0)" ::: "memory");
  __builtin_amdgcn_s_barrier();

  // ---- MFMA loop: 30 k-chunks, A quad-buffered 2 ahead, vmcnt(2) ----
  f32x4 zero4 = {0.f, 0.f, 0.f, 0.f};
  f32x4 acc[4][2];
  #pragma unroll
  for (int g = 0; g < 4; ++g) { acc[g][0] = zero4; acc[g][1] = zero4; }
  int cgrp = (lane >> 4) << 4;

  #pragma unroll
  for (int c = 0; c < 30; ++c) {
    int cn = (c + 2 < 30) ? (c + 2) : 29;
    gl_lds16(Wpk + ((((cn << 5) + ofw) << 6) + lane) * 8, A_lds[(c + 2) & 3] + (wave << 10));
    asm volatile("s_waitcnt vmcnt(2)" ::: "memory");
    __builtin_amdgcn_s_barrier();
    const char* Ab = A_lds[c & 3];
    int tap = c / 6, kk = c % 6;
    s16x8 av[4];
    #pragma unroll
    for (int g = 0; g < 4; ++g)
      av[g] = *(const s16x8*)(Ab + (((g << 1) + wrow) << 10) + (lane << 4));
    s16x8 bv[2];
    #pragma unroll
    for (int ni = 0; ni < 2; ++ni) {
      int row = (wcol << 5) + (ni << 4) + (lane & 15) + tap;
      int sw = (row & 7) << 4;
      const char* p = (kk < 2) ? (ldsx + (row << 7) + (((kk << 6) + cgrp) ^ sw))
                               : (ldsh + (row << 8) + ((((kk - 2) << 6) + cgrp) ^ sw));
      bv[ni] = *(const s16x8*)p;
    }
    #pragma unroll
    for (int g = 0; g < 4; ++g) {
      acc[g][0] = __builtin_amdgcn_mfma_f32_16x16x32_bf16(av[g], bv[0], acc[g][0], 0, 0, 0);
      acc[g][1] = __builtin_amdgcn_mfma_f32_16x16x32_bf16(av[g], bv[1], acc[g][1], 0, 0, 0);
    }
  }

  // ---- + bias, per-gate partial stats over this L-half ----
  int ch16 = (lane >> 4) << 2;
  int cbase = (cs << 5) + (wrow << 4) + ch16;     // hy channel base for r=0
  float sum[4], sq[4];
  #pragma unroll
  for (int g = 0; g < 4; ++g) {
    f32x4 bias = *(const f32x4*)(cb + (g << 7) + cbase);
    sum[g] = 0.f; sq[g] = 0.f;
    #pragma unroll
    for (int ni = 0; ni < 2; ++ni)
      #pragma unroll
      for (int r = 0; r < 4; ++r) {
        float v = acc[g][ni][r] + bias[r];
        acc[g][ni][r] = v;
        sum[g] += v; sq[g] += v * v;
      }
  }
  #pragma unroll
  for (int off = 1; off < 64; off <<= 1) {
    #pragma unroll
    for (int g = 0; g < 4; ++g) {
      sum[g] += __shfl_xor(sum[g], off);
      sq[g]  += __shfl_xor(sq[g], off);
    }
  }
  if (lane == 0) {
    #pragma unroll
    for (int g = 0; g < 4; ++g) { red[wave][g][0] = sum[g]; red[wave][g][1] = sq[g]; }
  }
  __syncthreads();

  // ---- partner exchange: write own partials, release flag, spin on partner ----
  int slot = (((t << 5) + b) << 3) + (cs << 1) + lh;
  if (tid == 0) {
    #pragma unroll
    for (int g = 0; g < 4; ++g) {
      float s = 0.f, q = 0.f;
      #pragma unroll
      for (int w = 0; w < 8; ++w) { s += red[w][g][0]; q += red[w][g][1]; }
      __hip_atomic_store(&stats[(slot << 3) + (g << 1)], s, __ATOMIC_RELAXED, __HIP_MEMORY_SCOPE_AGENT);
      __hip_atomic_store(&stats[(slot << 3) + (g << 1) + 1], q, __ATOMIC_RELAXED, __HIP_MEMORY_SCOPE_AGENT);
    }
    __hip_atomic_store(&flags[slot], 1, __ATOMIC_RELEASE, __HIP_MEMORY_SCOPE_AGENT);
    while (__hip_atomic_load(&flags[slot ^ 1], __ATOMIC_ACQUIRE, __HIP_MEMORY_SCOPE_AGENT) == 0) {}
  }
  __syncthreads();
  if (tid < 4) {   // g = tid; fixed order lh0+lh1 -> bitwise identical in both partners
    int base = (slot >> 1) << 4;
    float s = __hip_atomic_load(&stats[base + (tid << 1)], __ATOMIC_RELAXED, __HIP_MEMORY_SCOPE_AGENT)
            + __hip_atomic_load(&stats[base + 8 + (tid << 1)], __ATOMIC_RELAXED, __HIP_MEMORY_SCOPE_AGENT);
    float q = __hip_atomic_load(&stats[base + (tid << 1) + 1], __ATOMIC_RELAXED, __HIP_MEMORY_SCOPE_AGENT)
            + __hip_atomic_load(&stats[base + 8 + (tid << 1) + 1], __ATOMIC_RELAXED, __HIP_MEMORY_SCOPE_AGENT);
    const float inv = 1.0f / 8192.0f;
    float m = s * inv;
    smu[tid] = m;
    srs[tid] = rsqrtf(q * inv - m * m + EPS);
  }
  __syncthreads();

  // ---- GN apply + LSTM pointwise (wave-local) ----
  float w4[4][4], b4[4][4], muv[4], rsv[4];
  #pragma unroll
  for (int g = 0; g < 4; ++g) {
    muv[g] = smu[g]; rsv[g] = srs[g];
    #pragma unroll
    for (int r = 0; r < 4; ++r) {
      int c = (g << 7) + cbase + r;
      w4[g][r] = gnw[c]; b4[g][r] = gnb[c];
    }
  }
  float* outp = out + (((t << 5) + b) << 15);
  int lhalf = lane & 15;
  int gran = (wrow << 5) + (ch16 << 1);
  #pragma unroll
  for (int ni = 0; ni < 2; ++ni) {
    int ll = (wcol << 5) + (ni << 4) + lhalf;     // 0..127 within block
    int l = (lh << 7) + ll;
    u16 hp[4];
    #pragma unroll
    for (int r = 0; r < 4; ++r) {
      int c = cbase + r;
      float vi = (acc[0][ni][r] - muv[0]) * rsv[0] * w4[0][r] + b4[0][r];
      float vf = (acc[1][ni][r] - muv[1]) * rsv[1] * w4[1][r] + b4[1][r];
      float vg = (acc[2][ni][r] - muv[2]) * rsv[2] * w4[2][r] + b4[2][r];
      float vo = (acc[3][ni][r] - muv[3]) * rsv[3] * w4[3][r] + b4[3][r];
      int cxi = (((b << 7) + c) << 8) + l;
      float cyv = sigm(vf) * cx[cxi] + sigm(vi) * tanh_f(vg);
      float hyv = sigm(vo) * tanh_f(cyv);
      cx[cxi] = cyv;
      outp[(c << 8) + l] = hyv;
      hp[r] = f2bf(hyv);
      if (t == 31) {
        out[33554432 + cxi] = hyv;   // final hy
        out[34603008 + cxi] = cyv;   // final cy
      }
    }
    *(unsigned long long*)(hl + (ll << 6) + (gran ^ ((ll & 3) << 4))) =
        *(const unsigned long long*)hp;
  }
  __syncthreads();

  // ---- cooperative transposed h write: 32-ch stripe, this L-half ----
  {
    int ll = tid >> 2, k = tid & 3;
    int row = (lh << 7) + ll + 2;
    i32x4 v = *(const i32x4*)(hl + (ll << 6) + ((k << 4) ^ ((ll & 3) << 4)));
    char* dsth = (char*)hTw + b * 67584 + (row << 8) + ((((cs << 2) + k) << 4) ^ ((row & 7) << 4));
    *(i32x4*)dsth = v;
  }
}

// ---------- launch ----------
extern "C" void kernel_launch(void* const* d_in, const int* in_sizes, int n_in,
                              void* d_out, int out_size, void* d_ws, size_t ws_size,
                              hipStream_t stream) {
  const float* x  = (const float*)d_in[0];
  const float* cw = (const float*)d_in[1];
  const float* cb = (const float*)d_in[2];
  const float* gw = (const float*)d_in[3];
  const float* gb = (const float*)d_in[4];
  float* out = (float*)d_out;
  char* ws = (char*)d_ws;

  u16*   Wpk   = (u16*)(ws);                 //     983,040 B
  u16*   xT    = (u16*)(ws + 983040);        //  34,603,008 B
  u16*   hT    = (u16*)(ws + 35586048);      //   4,325,376 B (ping-pong)
  float* cx    = (float*)(ws + 39911424);    //   4,194,304 B
  float* stats = (float*)(ws + 44105728);    //     262,144 B
  int*   flags = (int*)(ws + 44367872);      //      32,768 B   (~44.4 MB)

  k_wcvt<<<1920, 256, 0, stream>>>(cw, Wpk);
  k_xtrans<<<1024, 256, 0, stream>>>(x, xT);
  k_init<<<512, 256, 0, stream>>>((i32x4*)hT, (i32x4*)cx, (i32x4*)flags);
  for (int t = 0; t < 32; ++t)
    k_step<<<256, 512, 0, stream>>>(Wpk, xT, hT, cb, gw, gb, cx, out, stats, flags, t);
}